// Round 12
// baseline (650.088 us; speedup 1.0000x reference)
//
#include <hip/hip_runtime.h>

// VectorQuantizer forward — outputs f32, concatenated:
//   out[0..8388608)        = z_e (STE forward value == z), NHWC order
//   out[8388608..8519680)  = argmin indices as f32, row (b,c,h) = z_e[b,h,:,c]
//   out[8519680]           = 0.25 * mean((z_q - z)^2)
//
// R11: 4 z-tiles per block (24 MFMA per e-fragment-set, 4 independent chains
// interleaved), depth-1 register prefetch of e-fragments, barrier-free main
// loop, compacted Phase-B flag list. Numerics verbatim R7/R9/R10 (passing).

#define N_Z 8388608   // 32*64*64*64
#define N_IDX 131072  // 32*64*64
#define K_EMB 1024
#define D_EMB 64
#define EPS_GAP 1.25e-4f  // rigorous flip bound ~7e-5; 1.8x safety

typedef __attribute__((ext_vector_type(8))) short bf16x8;
typedef __attribute__((ext_vector_type(4))) float f32x4;

// f32 -> bf16 bits, round-to-nearest-even
__device__ __forceinline__ unsigned short f2bf(float f) {
  unsigned u = __builtin_bit_cast(unsigned, f);
  unsigned r = 0x7fffu + ((u >> 16) & 1u);
  return (unsigned short)((u + r) >> 16);
}
__device__ __forceinline__ float bf2f(unsigned short b) {
  return __builtin_bit_cast(float, (unsigned)b << 16);
}

__global__ __launch_bounds__(256) void ek2f_kernel(
    const float* __restrict__ emb, float* __restrict__ ek2f) {
  int k = blockIdx.x * 256 + threadIdx.x;   // 4 blocks -> 1024
  const float* row = emb + (size_t)k * D_EMB;
  float s = 0.0f;
  for (int d = 0; d < D_EMB; d++) {
    float e = row[d];
    float sq = e * e;
    asm volatile("" : "+v"(sq));   // block FMA-contraction / reassociation
    s = s + sq;
  }
  ek2f[k] = s;
}

// Pre-swizzle emb into MFMA B-fragment-linear bf16 hi/lo arrays.
// Fragment order: idx = ((kt*2 + sp)*64 + l)*8 + i  where
//   k = kt*16 + (l&15),  w = sp*32 + (l>>4)*8 + i,  value = e[k][w].
__global__ __launch_bounds__(256) void ebf_prep_kernel(
    const float* __restrict__ emb, unsigned short* __restrict__ ehi,
    unsigned short* __restrict__ elo) {
  int gid = blockIdx.x * 256 + threadIdx.x;   // 32 blocks -> 8192
  int k = gid >> 3, oct = gid & 7;            // w-octet = oct*8 .. oct*8+7
  const float* src = emb + (size_t)k * 64 + oct * 8;
  int kt = k >> 4, sp = oct >> 2, l = (oct & 3) * 16 + (k & 15);
  size_t off = ((size_t)((kt * 2 + sp) * 64 + l)) * 8;
  bf16x8 h8, l8;
  #pragma unroll
  for (int i = 0; i < 8; i++) {
    float v = src[i];
    unsigned short hb = f2bf(v);
    float lf = v - bf2f(hb);       // exact
    h8[i] = (short)hb;
    l8[i] = (short)f2bf(lf);
  }
  *(bf16x8*)(ehi + off) = h8;
  *(bf16x8*)(elo + off) = l8;
}

#define MFMA_BF16 __builtin_amdgcn_mfma_f32_16x16x32_bf16

// One block per FOUR (b,h) tiles. 4 waves; wave wv owns c-rows [wv*16,wv*16+16)
// of all 4 tiles. Per kt: 4 e-fragment loads (prefetched 1 ahead) feed 24 MFMA
// in 4 independent chains. No barriers in the main loop.
__global__ __launch_bounds__(256) void vq_main_kernel(
    const float* __restrict__ z, const float* __restrict__ emb,
    const float* __restrict__ ek2g,
    const unsigned short* __restrict__ ehi_g,
    const unsigned short* __restrict__ elo_g,
    float* __restrict__ out0, float* __restrict__ out_idx,
    double* __restrict__ loss_acc) {
  __shared__ __align__(16) float zts[4][64][64];   // [ti][w][c] 64 KB
  __shared__ float sk2[K_EMB];                     // 4 KB
  __shared__ float sa[4][64];
  __shared__ int sidx[4][64];
  __shared__ int nflag;
  __shared__ int flist[256];
  __shared__ double lred[16];
  __shared__ float wrv[4];
  __shared__ int wri[4];

  const int t = threadIdx.x;
  const int bid4 = blockIdx.x;    // covers tiles bid4*4 .. bid4*4+3
  const int l = t & 63;           // lane
  const int cb = (t >> 6) * 16;   // wave c-base

  if (t == 0) nflag = 0;

  // ---- stage 4 z tiles [ti][w][c] AND write out[0] (= z) ----
  const float4* zt4 = (const float4*)(z + (size_t)bid4 * 16384);
  float4* o4 = (float4*)(out0 + (size_t)bid4 * 16384);
  #pragma unroll
  for (int q = 0; q < 16; q++) {
    int p = t + q * 256;          // 0..4095
    float4 v = zt4[p];
    int ti = p >> 10, p4 = p & 1023;
    *(float4*)&zts[ti][p4 >> 4][(p4 & 15) * 4] = v;
    o4[p] = v;
  }
  #pragma unroll
  for (int q = 0; q < 4; q++) sk2[t + q * 256] = ek2g[t + q * 256];
  __syncthreads();

  // ---- A[c]: strict sequential f32 sum of fl(z^2) (bit-exact, as R6/R7) ----
  {
    int ti = t >> 6, cc = t & 63;   // 256 threads cover 4x64
    float a = 0.0f;
    for (int w = 0; w < 64; w++) {
      float zf = zts[ti][w][cc];
      float sq = zf * zf;
      asm volatile("" : "+v"(sq));
      a = a + sq;
    }
    sa[ti][cc] = a;
  }

  // ---- persistent A-fragments (bf16 hi/lo) for 4 tiles ----
  bf16x8 zh0[4], zh1[4], zl0[4], zl1[4];
  {
    const int crow = cb + (l & 15);
    const int wb = (l >> 4) * 8;
    #pragma unroll
    for (int ti = 0; ti < 4; ti++) {
      #pragma unroll
      for (int i = 0; i < 8; i++) {
        float v0 = zts[ti][wb + i][crow];
        unsigned short h0 = f2bf(v0);
        zh0[ti][i] = (short)h0; zl0[ti][i] = (short)f2bf(v0 - bf2f(h0));
        float v1 = zts[ti][32 + wb + i][crow];
        unsigned short h1 = f2bf(v1);
        zh1[ti][i] = (short)h1; zl1[ti][i] = (short)f2bf(v1 - bf2f(h1));
      }
    }
  }
  __syncthreads();   // sa visible

  float A_[4][4];
  #pragma unroll
  for (int ti = 0; ti < 4; ti++)
    #pragma unroll
    for (int i = 0; i < 4; i++) A_[ti][i] = sa[ti][cb + (l >> 4) * 4 + i];

  float m1[4][4], m2[4][4];
  int i1[4][4];
  #pragma unroll
  for (int ti = 0; ti < 4; ti++)
    #pragma unroll
    for (int i = 0; i < 4; i++) { m1[ti][i] = 3.0e38f; m2[ti][i] = 3.0e38f; i1[ti][i] = 0; }

  // ---- main loop: 64 kt, depth-1 prefetch, barrier-free ----
  const uint4* hp = (const uint4*)ehi_g;   // uint4 index = kt*128 + l (+64 for sp1)
  const uint4* lp = (const uint4*)elo_g;
  uint4 c0 = hp[l], c1 = hp[l + 64], c2 = lp[l], c3 = lp[l + 64];
  for (int kt = 0; kt < 64; kt++) {
    uint4 n0 = c0, n1 = c1, n2 = c2, n3 = c3;
    if (kt < 63) {
      int nfi = (kt + 1) * 128 + l;
      n0 = hp[nfi]; n1 = hp[nfi + 64]; n2 = lp[nfi]; n3 = lp[nfi + 64];
    }
    bf16x8 bh0 = __builtin_bit_cast(bf16x8, c0);
    bf16x8 bh1 = __builtin_bit_cast(bf16x8, c1);
    bf16x8 bl0 = __builtin_bit_cast(bf16x8, c2);
    bf16x8 bl1 = __builtin_bit_cast(bf16x8, c3);

    f32x4 acc[4];
    #pragma unroll
    for (int ti = 0; ti < 4; ti++) acc[ti] = (f32x4){0.f, 0.f, 0.f, 0.f};
    // 6 steps x 4 tiles, interleaved so dependent MFMAs are 4 slots apart
    #pragma unroll
    for (int ti = 0; ti < 4; ti++) acc[ti] = MFMA_BF16(zh0[ti], bh0, acc[ti], 0, 0, 0);
    #pragma unroll
    for (int ti = 0; ti < 4; ti++) acc[ti] = MFMA_BF16(zh1[ti], bh1, acc[ti], 0, 0, 0);
    #pragma unroll
    for (int ti = 0; ti < 4; ti++) acc[ti] = MFMA_BF16(zh0[ti], bl0, acc[ti], 0, 0, 0);
    #pragma unroll
    for (int ti = 0; ti < 4; ti++) acc[ti] = MFMA_BF16(zh1[ti], bl1, acc[ti], 0, 0, 0);
    #pragma unroll
    for (int ti = 0; ti < 4; ti++) acc[ti] = MFMA_BF16(zl0[ti], bh0, acc[ti], 0, 0, 0);
    #pragma unroll
    for (int ti = 0; ti < 4; ti++) acc[ti] = MFMA_BF16(zl1[ti], bh1, acc[ti], 0, 0, 0);

    // C/D: col k = l&15, row c = cb + (l>>4)*4 + i
    const int k = kt * 16 + (l & 15);
    const float ck = sk2[k];
    #pragma unroll
    for (int ti = 0; ti < 4; ti++) {
      #pragma unroll
      for (int i = 0; i < 4; i++) {
        float sc = fmaf(-2.0f, acc[ti][i], A_[ti][i]) + ck;
        if (sc < m1[ti][i]) { m2[ti][i] = m1[ti][i]; m1[ti][i] = sc; i1[ti][i] = k; }
        else                { m2[ti][i] = fminf(m2[ti][i], sc); }  // == -> flag
      }
    }
    c0 = n0; c1 = n1; c2 = n2; c3 = n3;
  }

  // ---- 16-lane top-2 lex merge per (ti, c); flagged rows -> compact list ----
  #pragma unroll
  for (int ti = 0; ti < 4; ti++) {
    #pragma unroll
    for (int ci = 0; ci < 4; ci++) {
      float v1 = m1[ti][ci], v2 = m2[ti][ci];
      int ix = i1[ti][ci];
      #pragma unroll
      for (int m = 8; m; m >>= 1) {
        float ov1 = __shfl_xor(v1, m, 16);
        int oi1 = __shfl_xor(ix, m, 16);
        float ov2 = __shfl_xor(v2, m, 16);
        if (ov1 < v1)      { v2 = fminf(v1, ov2); v1 = ov1; ix = oi1; }
        else if (ov1 > v1) { v2 = fminf(v2, ov1); }
        else               { v2 = v1; ix = min(ix, oi1); }   // tie -> force flag
      }
      if ((l & 15) == 0) {
        int c = cb + (l >> 4) * 4 + ci;
        sidx[ti][c] = ix;
        if (v2 - v1 <= EPS_GAP) {
          int pos = atomicAdd(&nflag, 1);
          flist[pos] = ti * 64 + c;
        }
      }
    }
  }
  __syncthreads();

  // ---- Phase B: exact re-scan of flagged rows (R7 semantics) ----
  const int nf = nflag;
  for (int f = 0; f < nf; f++) {
    int tc = flist[f];
    int ti = tc >> 6, c = tc & 63;
    float A = sa[ti][c];
    float lm = 3.0e38f;
    int li = 0;
    #pragma unroll
    for (int r = 0; r < 4; r++) {
      int k = t + 256 * r;
      double B = 0.0;
      const float4* e4 = (const float4*)(emb + (size_t)k * 64);
      for (int w4 = 0; w4 < 16; w4++) {
        float4 e = e4[w4];
        B += (double)zts[ti][w4 * 4 + 0][c] * (double)e.x;
        B += (double)zts[ti][w4 * 4 + 1][c] * (double)e.y;
        B += (double)zts[ti][w4 * 4 + 2][c] * (double)e.z;
        B += (double)zts[ti][w4 * 4 + 3][c] * (double)e.w;
      }
      float Bf = (float)B;
      float t1 = A - 2.0f * Bf;              // 2*Bf exact -> single rounding
      float sc = t1 + sk2[k];
      if (sc < lm) { lm = sc; li = k; }      // k ascending -> first-min kept
    }
    #pragma unroll
    for (int m = 32; m; m >>= 1) {
      float ov = __shfl_xor(lm, m);
      int oi = __shfl_xor(li, m);
      if (ov < lm || (ov == lm && oi < li)) { lm = ov; li = oi; }
    }
    if ((t & 63) == 0) { wrv[t >> 6] = lm; wri[t >> 6] = li; }
    __syncthreads();
    if (t == 0) {
      float bv = wrv[0]; int bi = wri[0];
      #pragma unroll
      for (int q = 1; q < 4; q++) {
        if (wrv[q] < bv || (wrv[q] == bv && wri[q] < bi)) { bv = wrv[q]; bi = wri[q]; }
      }
      sidx[ti][c] = bi;
    }
    __syncthreads();
  }

  // ---- write indices ----
  {
    int ti = t >> 6, cc = t & 63;
    int tile = bid4 * 4 + ti;
    int b = tile >> 6, h = tile & 63;
    out_idx[(size_t)b * 4096 + cc * 64 + h] = (float)sidx[ti][cc];
  }

  // ---- loss: sum (z - e[idx])^2 in f64 (R7 semantics, 4 tiles) ----
  double ls = 0.0;
  #pragma unroll
  for (int ti = 0; ti < 4; ti++) {
    #pragma unroll
    for (int ci = 0; ci < 4; ci++) {
      int c = (t >> 4) * 4 + ci;
      const float* er = emb + (size_t)sidx[ti][c] * 64;
      #pragma unroll
      for (int s = 0; s < 4; s++) {
        int w = (t & 15) + 16 * s;
        double d = (double)zts[ti][w][c] - (double)er[w];
        ls += d * d;
      }
    }
  }
  #pragma unroll
  for (int m = 8; m; m >>= 1) ls += __shfl_xor(ls, m, 16);
  if ((t & 15) == 0) lred[t >> 4] = ls;
  __syncthreads();
  if (t == 0) {
    double s = 0.0;
    #pragma unroll
    for (int q = 0; q < 16; q++) s += lred[q];
    atomicAdd(loss_acc, s);
  }
}

__global__ void loss_final_kernel(const double* __restrict__ acc,
                                  float* __restrict__ out_loss) {
  *out_loss = (float)(0.25 * (*acc) / (double)N_Z);
}

extern "C" void kernel_launch(void* const* d_in, const int* in_sizes, int n_in,
                              void* d_out, int out_size, void* d_ws, size_t ws_size,
                              hipStream_t stream) {
  const float* z = (const float*)d_in[0];     // [32,64,64,64] NHWC
  const float* emb = (const float*)d_in[1];   // [1024,64]
  float* out = (float*)d_out;

  float* ek2f = (float*)d_ws;                              // 4 KB @ 0
  double* lacc = (double*)((char*)d_ws + 4096);            // 8 B
  unsigned short* ehi = (unsigned short*)((char*)d_ws + 8192);    // 128 KB
  unsigned short* elo = (unsigned short*)((char*)d_ws + 8192 + 131072); // 128 KB

  (void)hipMemsetAsync(lacc, 0, sizeof(double), stream);
  ek2f_kernel<<<4, 256, 0, stream>>>(emb, ek2f);
  ebf_prep_kernel<<<32, 256, 0, stream>>>(emb, ehi, elo);
  vq_main_kernel<<<512, 256, 0, stream>>>(z, emb, ek2f, ehi, elo,
                                          out, out + N_Z, lacc);
  loss_final_kernel<<<1, 1, 0, stream>>>(lacc, out + N_Z + N_IDX);
}